// Round 10
// baseline (77.414 us; speedup 1.0000x reference)
//
#include <hip/hip_runtime.h>
#include <hip/hip_bf16.h>

// TT embedding — R10 PROBE ROUND. Same math/structure as R9 (best: 31.3 us),
// but the per-token pipeline repeats reps=3x (identical values stored each
// rep; `v` laundered through empty asm per rep to defeat LICM/CSE). Purpose:
// make our dispatch ~90us so it beats the harness's 40-45us fill dispatches
// into rocprof top-5 and we finally SEE VALUBusy/Occupancy/FETCH/WRITE for
// this kernel class. dur_us this round is sacrificial (~3x).
//
// out[v,d] = sum_{r1..r4} c0[0,i0,r1] c1[r1,i1,r2] c2[r2,i2,r3] c3[r3,i3,r4] c4[r4,i4,0]
//   i0=v>>11, i1=(v>>6)&31, i2=(v>>1)&31, i3=(v&1)*16+(d>>6), i4=d&63

typedef float f32x4 __attribute__((ext_vector_type(4)));

#define STEP(WV, k)                              \
    acc.x = fmaf(WV, c4v[k].x, acc.x);           \
    acc.y = fmaf(WV, c4v[k].y, acc.y);           \
    acc.z = fmaf(WV, c4v[k].z, acc.z);           \
    acc.w = fmaf(WV, c4v[k].w, acc.w);

__global__ __launch_bounds__(256) void tt_embed_kernel(
    const float* __restrict__ c0,   // 32*16
    const float* __restrict__ c1,   // 16*32*16
    const float* __restrict__ c2,   // 16*32*16
    const float* __restrict__ c3,   // 16*32*16
    const float* __restrict__ c4,   // 16*64
    const int*   __restrict__ idx,  // n_tokens
    float*       __restrict__ out,  // n_tokens x 1024
    int n_tokens, int reps)
{
    const int t = threadIdx.x;
    const int g = t >> 4;            // token group within block (0..15)
    const int r = t & 15;            // lane within group
    const int token = blockIdx.x * 16 + g;
    const int v0 = (token < n_tokens) ? idx[token] : 0;

    __shared__ float w4[16][16][20];   // [g][d1][r4 pad 20]

    // c4 column slice: lane covers output cols i4 = r*4 .. r*4+3
    float4 c4v[16];
    #pragma unroll
    for (int r4 = 0; r4 < 16; ++r4)
        c4v[r4] = *(const float4*)(c4 + (r4 << 6) + (r << 2));

    for (int rep = 0; rep < reps; ++rep) {
        int v = v0;
        asm volatile("" : "+v"(v));   // opaque per-rep: defeats LICM/CSE

        // ---- Stage 1: lane r owns w2[r]
        float w2r = 0.f;
        {
            const int i0 = (v >> 11) & 31;
            const int i1 = (v >> 6) & 31;
            #pragma unroll
            for (int r1 = 0; r1 < 16; ++r1)
                w2r = fmaf(c0[i0 * 16 + r1], c1[(r1 * 32 + i1) * 16 + r], w2r);
        }

        // ---- Stage 2: lane r owns w3[r]
        float w3r = 0.f;
        {
            const int i2 = (v >> 1) & 31;
            #pragma unroll
            for (int r2 = 0; r2 < 16; ++r2)
                w3r = fmaf(__shfl(w2r, r2, 16), c2[(r2 * 32 + i2) * 16 + r], w3r);
        }

        // ---- Stage 3: lane r computes w4 row for d1 = r
        {
            const int i3 = ((v & 1) << 4) + r;
            float4 a0 = {0,0,0,0}, a1 = {0,0,0,0}, a2 = {0,0,0,0}, a3 = {0,0,0,0};
            #pragma unroll
            for (int r3 = 0; r3 < 16; ++r3) {
                const float wv = __shfl(w3r, r3, 16);
                const float4* row = (const float4*)(c3 + (r3 * 32 + i3) * 16);
                float4 b0 = row[0], b1 = row[1], b2 = row[2], b3 = row[3];
                a0.x = fmaf(wv, b0.x, a0.x); a0.y = fmaf(wv, b0.y, a0.y);
                a0.z = fmaf(wv, b0.z, a0.z); a0.w = fmaf(wv, b0.w, a0.w);
                a1.x = fmaf(wv, b1.x, a1.x); a1.y = fmaf(wv, b1.y, a1.y);
                a1.z = fmaf(wv, b1.z, a1.z); a1.w = fmaf(wv, b1.w, a1.w);
                a2.x = fmaf(wv, b2.x, a2.x); a2.y = fmaf(wv, b2.y, a2.y);
                a2.z = fmaf(wv, b2.z, a2.z); a2.w = fmaf(wv, b2.w, a2.w);
                a3.x = fmaf(wv, b3.x, a3.x); a3.y = fmaf(wv, b3.y, a3.y);
                a3.z = fmaf(wv, b3.z, a3.z); a3.w = fmaf(wv, b3.w, a3.w);
            }
            float4* wrow = (float4*)&w4[g][r][0];
            wrow[0] = a0; wrow[1] = a1; wrow[2] = a2; wrow[3] = a3;
        }

        // ---- Stage 4: 2-deep pipeline over k = d1
        {
            const float4* wr0 = (const float4*)&w4[g][0][0];
            float4 wa = wr0[0], wb = wr0[1], wc = wr0[2], wd = wr0[3];

            float* outp = out + (size_t)token * 1024 + (r << 2);

            #pragma unroll
            for (int k = 0; k < 16; ++k) {
                float4 na, nb, nc, nd;
                if (k + 1 < 16) {
                    const float4* wn = (const float4*)&w4[g][k + 1][0];
                    na = wn[0]; nb = wn[1]; nc = wn[2]; nd = wn[3];
                }

                float4 acc = {0,0,0,0};
                STEP(wa.x,  0) STEP(wa.y,  1) STEP(wa.z,  2) STEP(wa.w,  3)
                STEP(wb.x,  4) STEP(wb.y,  5) STEP(wb.z,  6) STEP(wb.w,  7)
                STEP(wc.x,  8) STEP(wc.y,  9) STEP(wc.z, 10) STEP(wc.w, 11)
                STEP(wd.x, 12) STEP(wd.y, 13) STEP(wd.z, 14) STEP(wd.w, 15)

                if (token < n_tokens)
                    __builtin_nontemporal_store(*(const f32x4*)&acc,
                                                (f32x4*)(outp + (k << 6)));

                wa = na; wb = nb; wc = nc; wd = nd;
            }
        }
        __syncthreads();   // keep reps' LDS reuse ordered across the block's waves
    }
}

extern "C" void kernel_launch(void* const* d_in, const int* in_sizes, int n_in,
                              void* d_out, int out_size, void* d_ws, size_t ws_size,
                              hipStream_t stream) {
    const float* c0  = (const float*)d_in[0];
    const float* c1  = (const float*)d_in[1];
    const float* c2  = (const float*)d_in[2];
    const float* c3  = (const float*)d_in[3];
    const float* c4  = (const float*)d_in[4];
    const int*   idx = (const int*)d_in[5];
    float* out = (float*)d_out;

    const int n_tokens = in_sizes[5];              // 8 * 2048 = 16384
    const int grid = (n_tokens + 15) / 16;         // 1024
    tt_embed_kernel<<<grid, 256, 0, stream>>>(c0, c1, c2, c3, c4, idx, out,
                                              n_tokens, /*reps=*/3);
}

// Round 11
// 26.280 us; speedup vs baseline: 2.9457x; 2.9457x over previous
//
#include <hip/hip_runtime.h>
#include <hip/hip_bf16.h>

// TT embedding: vocab 65536, dim 1024, rank 16.
// out[v,d] = sum_{r1..r4} c0[0,i0,r1] c1[r1,i1,r2] c2[r2,i2,r3] c3[r3,i3,r4] c4[r4,i4,0]
//   i0=v>>11, i1=(v>>6)&31, i2=(v>>1)&31, i3=(v&1)*16+(d>>6), i4=d&63
//
// R10 probe findings: (1) SQ_LDS_BANK_CONFLICT=3.1M — w4 group stride 320w ≡ 0
// mod 32 made stage-4 reads 4-way conflicted across the wave's 4 groups.
// (2) stage-3 c3 gathers touched 64 cache lines per wave-instr (~4096 L1
// line-cycles/wave ≈ the whole 27us/rep). R11 (R9 structure kept, 0 barriers):
//  - stage 3 loads the group's contiguous 1KB c3 block COALESCED: lane r reads
//    float4 #(l*16+r) -> owns quarter (r&3) of rows {l*4+(r>>2)}; 16 lines per
//    wave-instr instead of 64. Per-element FMA order identical to R9 (absmax 0).
//  - w4 LDS layout: row stride 24 words, group stride 392 words (392%32=8):
//    stage-4 group reads hit disjoint banks {0,8,16,24}; stage-3 writes <=2-way.

typedef float f32x4 __attribute__((ext_vector_type(4)));

#define GSTRIDE 392   // words per token group (16 rows x 24 + 8 pad)
#define RSTRIDE 24    // words per w4 row

#define STEP(WV, k)                              \
    acc.x = fmaf(WV, c4v[k].x, acc.x);           \
    acc.y = fmaf(WV, c4v[k].y, acc.y);           \
    acc.z = fmaf(WV, c4v[k].z, acc.z);           \
    acc.w = fmaf(WV, c4v[k].w, acc.w);

__global__ __launch_bounds__(256) void tt_embed_kernel(
    const float* __restrict__ c0,   // 32*16
    const float* __restrict__ c1,   // 16*32*16
    const float* __restrict__ c2,   // 16*32*16
    const float* __restrict__ c3,   // 16*32*16
    const float* __restrict__ c4,   // 16*64
    const int*   __restrict__ idx,  // n_tokens
    float*       __restrict__ out,  // n_tokens x 1024
    int n_tokens)
{
    const int t = threadIdx.x;
    const int g = t >> 4;            // token group within block (0..15)
    const int r = t & 15;            // lane within group
    const int token = blockIdx.x * 16 + g;
    const int v = (token < n_tokens) ? idx[token] : 0;

    __shared__ float w4s[16 * GSTRIDE];   // ~25 KB

    // ---- c4 column slice: lane covers output cols i4 = r*4 .. r*4+3
    float4 c4v[16];
    #pragma unroll
    for (int r4 = 0; r4 < 16; ++r4)
        c4v[r4] = *(const float4*)(c4 + (r4 << 6) + (r << 2));

    // ---- Stage 1: lane r owns w2[r] = sum_r1 c0[i0,r1] * c1[r1,i1,r]
    float w2r = 0.f;
    {
        const int i0 = (v >> 11) & 31;
        const int i1 = (v >> 6) & 31;
        #pragma unroll
        for (int r1 = 0; r1 < 16; ++r1)
            w2r = fmaf(c0[i0 * 16 + r1], c1[(r1 * 32 + i1) * 16 + r], w2r);
    }

    // ---- Stage 2: lane r owns w3[r] = sum_r2 w2[r2] * c2[r2,i2,r]
    float w3r = 0.f;
    {
        const int i2 = (v >> 1) & 31;
        #pragma unroll
        for (int r2 = 0; r2 < 16; ++r2)
            w3r = fmaf(__shfl(w2r, r2, 16), c2[(r2 * 32 + i2) * 16 + r], w3r);
    }

    // ---- Stage 3 (coalesced): the group's c3 data for r3 is ONE contiguous
    // 1KB block (rows i3 = vlow*16 + 0..15). Lane r reads float4 #(l*16+r):
    // quarter q=(r&3) of row j=l*4+(r>>2). acc_l accumulates that quarter.
    {
        const int vlow16 = (v & 1) << 4;
        float4 a0 = {0,0,0,0}, a1 = {0,0,0,0}, a2 = {0,0,0,0}, a3 = {0,0,0,0};
        #pragma unroll
        for (int r3 = 0; r3 < 16; ++r3) {
            const float wv = __shfl(w3r, r3, 16);
            const float* blk = c3 + ((r3 * 32 + vlow16) << 4);   // 256 floats
            float4 b0 = *(const float4*)(blk       + (r << 2));
            float4 b1 = *(const float4*)(blk +  64 + (r << 2));
            float4 b2 = *(const float4*)(blk + 128 + (r << 2));
            float4 b3 = *(const float4*)(blk + 192 + (r << 2));
            a0.x = fmaf(wv, b0.x, a0.x); a0.y = fmaf(wv, b0.y, a0.y);
            a0.z = fmaf(wv, b0.z, a0.z); a0.w = fmaf(wv, b0.w, a0.w);
            a1.x = fmaf(wv, b1.x, a1.x); a1.y = fmaf(wv, b1.y, a1.y);
            a1.z = fmaf(wv, b1.z, a1.z); a1.w = fmaf(wv, b1.w, a1.w);
            a2.x = fmaf(wv, b2.x, a2.x); a2.y = fmaf(wv, b2.y, a2.y);
            a2.z = fmaf(wv, b2.z, a2.z); a2.w = fmaf(wv, b2.w, a2.w);
            a3.x = fmaf(wv, b3.x, a3.x); a3.y = fmaf(wv, b3.y, a3.y);
            a3.z = fmaf(wv, b3.z, a3.z); a3.w = fmaf(wv, b3.w, a3.w);
        }
        // scatter quarters to w4 rows (within-wave LDS, no barrier needed)
        const int q4 = (r & 3) << 2;        // word offset within row
        const int rr = r >> 2;
        float* wb = &w4s[g * GSTRIDE + q4];
        *(float4*)(wb + ( 0 + rr) * RSTRIDE) = a0;
        *(float4*)(wb + ( 4 + rr) * RSTRIDE) = a1;
        *(float4*)(wb + ( 8 + rr) * RSTRIDE) = a2;
        *(float4*)(wb + (12 + rr) * RSTRIDE) = a3;
    }

    // ---- Stage 4: out[token, k*64 + r*4 ..+3] = sum_r4 w4[k][r4] * c4v[r4]
    // 2-deep pipeline: k+1's row reads issue before k's 64-FMA block.
    {
        const float4* wr0 = (const float4*)&w4s[g * GSTRIDE];
        float4 wa = wr0[0], wb = wr0[1], wc = wr0[2], wd = wr0[3];

        float* outp = out + (size_t)token * 1024 + (r << 2);

        #pragma unroll
        for (int k = 0; k < 16; ++k) {
            float4 na, nb, nc, nd;
            if (k + 1 < 16) {                 // compile-time after unroll
                const float4* wn = (const float4*)&w4s[g * GSTRIDE + (k + 1) * RSTRIDE];
                na = wn[0]; nb = wn[1]; nc = wn[2]; nd = wn[3];
            }

            float4 acc = {0,0,0,0};
            STEP(wa.x,  0) STEP(wa.y,  1) STEP(wa.z,  2) STEP(wa.w,  3)
            STEP(wb.x,  4) STEP(wb.y,  5) STEP(wb.z,  6) STEP(wb.w,  7)
            STEP(wc.x,  8) STEP(wc.y,  9) STEP(wc.z, 10) STEP(wc.w, 11)
            STEP(wd.x, 12) STEP(wd.y, 13) STEP(wd.z, 14) STEP(wd.w, 15)

            if (token < n_tokens)
                __builtin_nontemporal_store(*(const f32x4*)&acc,
                                            (f32x4*)(outp + (k << 6)));

            wa = na; wb = nb; wc = nc; wd = nd;
        }
    }
}

extern "C" void kernel_launch(void* const* d_in, const int* in_sizes, int n_in,
                              void* d_out, int out_size, void* d_ws, size_t ws_size,
                              hipStream_t stream) {
    const float* c0  = (const float*)d_in[0];
    const float* c1  = (const float*)d_in[1];
    const float* c2  = (const float*)d_in[2];
    const float* c3  = (const float*)d_in[3];
    const float* c4  = (const float*)d_in[4];
    const int*   idx = (const int*)d_in[5];
    float* out = (float*)d_out;

    const int n_tokens = in_sizes[5];              // 8 * 2048 = 16384
    const int grid = (n_tokens + 15) / 16;         // 1024
    tt_embed_kernel<<<grid, 256, 0, stream>>>(c0, c1, c2, c3, c4, idx, out, n_tokens);
}